// Round 10
// baseline (416.653 us; speedup 1.0000x reference)
//
#include <hip/hip_runtime.h>
#include <hip/hip_bf16.h>

#define NPTS 256
#define NB   4
#define KNN  27
#define EPSV 1e-5f

typedef unsigned short u16;
typedef _Float16 f16;
typedef __attribute__((ext_vector_type(8))) _Float16 f16x8;
typedef __attribute__((ext_vector_type(4))) float f32x4;

// ---------------- workspace layout (bytes); ws = 256 MiB ----------------
#define OFF_IDX    0           // idxT [k][pt]: 27*1024*4 = 110592
#define OFF_XYZ    131072      // 4*256*32*2 = 65536   f16 [b][n][32]
#define OFF_A0     262144      // 128*32*2    = 8192
#define OFF_A1     270336      // 384*96*2    = 73728
#define OFF_A2     344064      // 1536*384*2  = 1179648
#define OFF_A3     1523712     // 6144*1536*2 = 18874368
#define OFF_A4     20398080    // 256*8160*2  = 4177920
#define OFF_PQ     24576000    // f16: 3*4*6144*256*2 = 37748736 partial planes
#define OFF_XC     62324736    // 4*256*8160*2 = 16711680  f16 [b][n][8160]
#define OFF_Y      79036416    // f16: 8*4*256*256*2 = 4194304
// end ~83 MB

__device__ __forceinline__ float f16_lo(unsigned w) {
    union { u16 u; f16 h; } c; c.u = (u16)(w & 0xffffu); return (float)c.h;
}
__device__ __forceinline__ float f16_hi(unsigned w) {
    union { u16 u; f16 h; } c; c.u = (u16)(w >> 16); return (float)c.h;
}
__device__ __forceinline__ u16 f16_bits(float f) {
    union { f16 h; u16 u; } c; c.h = (f16)f; return c.u;
}
__device__ __forceinline__ float f16_val(u16 u) {
    union { u16 u; f16 h; } c; c.u = u; return (float)c.h;
}

__device__ __forceinline__ float dist3_nocontract(float ax, float ay, float az,
                                                  float bx, float by, float bz) {
#pragma clang fp contract(off)
    float dx = bx - ax, dy = by - ay, dz = bz - az;
    float s = dx * dx;
    s = s + dy * dy;
    s = s + dz * dz;
    return s;
}

// ---------------- merged kNN + weight prep (one dispatch) -------------------
// blocks [0,256): kNN, 4 points/block; writes idxT[k][pt] (transposed for
// coalesced gather reads) + xyz f16.
// blocks [256,9472): weight transform + f16 convert.
__global__ __launch_bounds__(256) void prep_knn(
    const float* __restrict__ x, int* __restrict__ idxT,
    const float* __restrict__ w0, const float* __restrict__ w1,
    const float* __restrict__ w2, const float* __restrict__ w3,
    const float* __restrict__ w4, char* __restrict__ ws)
{
    int bid = blockIdx.x;
    if (bid < 256) {
        int wv = threadIdx.x >> 6;
        int lane = threadIdx.x & 63;
        int pt = bid * 4 + wv;          // 0..1023
        int b = pt >> 8, n = pt & 255;
        f16* xyz = (f16*)(ws + OFF_XYZ);

        float xp0 = x[pt * 3 + 0];
        float xp1 = x[pt * 3 + 1];
        float xp2 = x[pt * 3 + 2];

        if (lane < 32) {
            float v = (lane < 3) ? x[pt * 3 + lane] : 0.f;
            xyz[((long)b * NPTS + n) * 32 + lane] = (f16)v;
        }

        unsigned long long key[4];
#pragma unroll
        for (int u = 0; u < 4; ++u) {
            int j = lane + 64 * u;
            int gj = b * NPTS + j;
            float d = dist3_nocontract(xp0, xp1, xp2,
                                       x[gj * 3 + 0], x[gj * 3 + 1], x[gj * 3 + 2]);
            key[u] = ((unsigned long long)__float_as_uint(d) << 32) | (unsigned int)j;
        }
        for (int r = 0; r < KNN; ++r) {
            unsigned long long m = key[0];
            m = key[1] < m ? key[1] : m;
            m = key[2] < m ? key[2] : m;
            m = key[3] < m ? key[3] : m;
#pragma unroll
            for (int off = 32; off; off >>= 1) {
                unsigned long long o = __shfl_xor(m, off);
                m = o < m ? o : m;
            }
            if (lane == 0) idxT[r * 1024 + pt] = (int)(m & 0xffffffffu);
#pragma unroll
            for (int u = 0; u < 4; ++u)
                if (key[u] == m) key[u] = ~0ULL;
        }
        return;
    }

    // weight prep; cumulative job blocks: 128, 512, 2048, 8192, 9216
    bid -= 256;
    const float* w;
    int r, cbase = 0, M, Co, K, Kpad, mode;
    long offA;
    if (bid < 128)      { w = w0; r = bid;        M = 96;   Co = 48;   K = 3;    Kpad = 32;   mode = 0; offA = OFF_A0; }
    else if (bid < 512) { w = w1; r = bid - 128;  M = 384;  Co = 192;  K = 96;   Kpad = 96;   mode = 0; offA = OFF_A1; }
    else if (bid < 2048){ w = w2; r = bid - 512;  M = 1536; Co = 768;  K = 384;  Kpad = 384;  mode = 0; offA = OFF_A2; }
    else if (bid < 8192){ w = w3; r = bid - 2048; M = 6144; Co = 3072; K = 1536; Kpad = 1536; mode = 0; offA = OFF_A3; }
    else { int loc = bid - 8192; w = w4; r = loc >> 2; cbase = (loc & 3) * 2048;
           M = 256; Co = 0; K = 8160; Kpad = 8160; mode = 1; offA = OFF_A4; }

    int c0 = cbase + threadIdx.x * 8;
    if (c0 >= Kpad) return;
    f16* A = (f16*)(ws + offA);

    f16x8 hv;
#pragma unroll
    for (int j = 0; j < 8; ++j) {
        int c = c0 + j;
        float a = 0.f;
        if (c < K && r < M) {
            if (mode == 1) a = w[(long)r * K + c];
            else if (r < Co) a = w[(long)r * (2 * K) + c];
            else {
                long base = (long)(r - Co) * (2 * K);
                a = w[base + K + c] - w[base + c];
            }
        }
        hv[j] = (f16)a;
    }
    *(f16x8*)&A[(long)r * Kpad + c0] = hv;
}

// ---------------- f16 MFMA GEMM, split-K into private f16 partial planes ----
// (frozen from R9) Block 128x128, BK=32; wave 64x64 = 4x4 mfma_f32_16x16x32_f16.
__global__ __launch_bounds__(256) void gemm_mfma(
    const f16* __restrict__ A, const f16* __restrict__ B,
    u16* __restrict__ out, int M, int Kpad, int K,
    int ldF, long bsF, long bsO, int nsplit, long pstride)
{
    __shared__ u16 sA[128][40], sB[128][40];

    int bz = blockIdx.z;
    int b = bz / nsplit, slice = bz - b * nsplit;
    int kchunk = (((K + nsplit - 1) / nsplit) + 31) & ~31;
    int kstart = slice * kchunk;
    int kend = K < kstart + kchunk ? K : kstart + kchunk;

    const f16* pB = B + (long)b * bsF;
    u16* Ob = out + (long)slice * pstride + (long)b * bsO;

    int m0 = blockIdx.x * 128, n0 = blockIdx.y * 128;
    int tid = threadIdx.x, lane = tid & 63, wid = tid >> 6;
    int wm = (wid >> 1) * 64, wn = (wid & 1) * 64;
    int lrow = lane & 15, quad = lane >> 4;

    int srow = tid >> 1;            // 0..127
    int sk = (tid & 1) * 16;        // 0,16

    const f16* gA = A + (long)(m0 + srow) * Kpad + sk;
    const f16* gB = pB + (long)(n0 + srow) * ldF + sk;

    f32x4 acc[4][4] = {};

    for (int kk = kstart; kk < kend; kk += 32) {
        f16x8 a0 = *(const f16x8*)(gA + kk);
        f16x8 a1 = *(const f16x8*)(gA + kk + 8);
        f16x8 b0 = *(const f16x8*)(gB + kk);
        f16x8 b1 = *(const f16x8*)(gB + kk + 8);

        __syncthreads();

        *(f16x8*)&sA[srow][sk] = a0;
        *(f16x8*)&sA[srow][sk + 8] = a1;
        *(f16x8*)&sB[srow][sk] = b0;
        *(f16x8*)&sB[srow][sk + 8] = b1;

        __syncthreads();

        f16x8 fb[4];
#pragma unroll
        for (int nt = 0; nt < 4; ++nt)
            fb[nt] = *(const f16x8*)&sB[wn + nt * 16 + lrow][quad * 8];
#pragma unroll
        for (int mt = 0; mt < 4; ++mt) {
            f16x8 fa = *(const f16x8*)&sA[wm + mt * 16 + lrow][quad * 8];
#pragma unroll
            for (int nt = 0; nt < 4; ++nt)
                acc[mt][nt] = __builtin_amdgcn_mfma_f32_16x16x32_f16(fa, fb[nt], acc[mt][nt], 0, 0, 0);
        }
    }

#pragma unroll
    for (int mt = 0; mt < 4; ++mt)
#pragma unroll
        for (int nt = 0; nt < 4; ++nt) {
            int C = n0 + wn + nt * 16 + lrow;
            int Rb = m0 + wm + mt * 16 + quad * 4;
#pragma unroll
            for (int r = 0; r < 4; ++r) {
                int R = Rb + r;
                if (R < M) Ob[(long)R * NPTS + C] = f16_bits(acc[mt][nt][r]);
            }
        }
}

// ---------------- gather16: gather + stats + BN/lrelu + tp + transpose ------
// 1024 threads; thread t owns point (b = t>>8, n = t&255). Block owns 16
// consecutive channels o0..o0+15. P packed 32 B/point in LDS -> 2 ds_read_b128
// per neighbor serve all 16 channels. Writes xc[b][n][offc+o0..] (32 B) and
// the tp copy at offc+Co+o0 (32 B) directly -- transpose stage eliminated.
__global__ __launch_bounds__(1024) void gather16(
    const u16* __restrict__ PQ, long pstride, int nsplit,
    const int* __restrict__ idxT,
    const float* __restrict__ g, const float* __restrict__ beta,
    u16* __restrict__ xc, int Co, int offc)
{
    __shared__ uint4 pP[NB][NPTS][2];     // 32 KB packed f16 x16 per point
    __shared__ uint4 vls[2][NPTS][2];     // 16 KB val for flat batches 0,1
    __shared__ float red[16][32];         // 2 KB wave partials
    __shared__ float sctt[32];            // sc[16], tt[16]

    int t = threadIdx.x;
    int b = t >> 8, n = t & 255;
    int wv = t >> 6, lane = t & 63;
    int o0 = blockIdx.x * 16;

    long base_p = ((long)b * 2 * Co + o0) * NPTS + n;
    long base_q = base_p + (long)Co * NPTS;

    // ---- load P/Q (16 channels), summing partial planes in fp32
    float q[16];
    {
        unsigned pk[8];
#pragma unroll
        for (int c = 0; c < 16; ++c) {
            float pv = 0.f, qv = 0.f;
            for (int sp = 0; sp < nsplit; ++sp) {
                pv += f16_val(PQ[sp * pstride + base_p + c * NPTS]);
                qv += f16_val(PQ[sp * pstride + base_q + c * NPTS]);
            }
            q[c] = qv;
            u16 hb = f16_bits(pv);
            if (c & 1) pk[c >> 1] |= ((unsigned)hb << 16);
            else pk[c >> 1] = (unsigned)hb;
        }
        uint4 w0, w1;
        w0.x = pk[0]; w0.y = pk[1]; w0.z = pk[2]; w0.w = pk[3];
        w1.x = pk[4]; w1.y = pk[5]; w1.z = pk[6]; w1.w = pk[7];
        pP[b][n][0] = w0;
        pP[b][n][1] = w1;
    }
    __syncthreads();

    // ---- neighbor loop
    float s[16], ss[16], mx[16], mn[16];
#pragma unroll
    for (int c = 0; c < 16; ++c) {
        s[c] = 0.f; ss[c] = 0.f;
        mx[c] = -__builtin_inff(); mn[c] = __builtin_inff();
    }
#pragma unroll 1
    for (int k = 0; k < KNN; ++k) {
        int j = idxT[k * 1024 + t];           // coalesced
        uint4 w0 = pP[b][j][0];
        uint4 w1 = pP[b][j][1];
        unsigned pw[8] = {w0.x, w0.y, w0.z, w0.w, w1.x, w1.y, w1.z, w1.w};
#pragma unroll
        for (int c = 0; c < 16; ++c) {
            float h = ((c & 1) ? f16_hi(pw[c >> 1]) : f16_lo(pw[c >> 1])) + q[c];
            s[c] += h;
            ss[c] += h * h;
            mx[c] = fmaxf(mx[c], h);
            mn[c] = fminf(mn[c], h);
        }
    }

    // ---- block-wide stats reduction
#pragma unroll
    for (int c = 0; c < 16; ++c)
#pragma unroll
        for (int off = 32; off; off >>= 1) {
            s[c] += __shfl_xor(s[c], off);
            ss[c] += __shfl_xor(ss[c], off);
        }
    if (lane == 0) {
#pragma unroll
        for (int c = 0; c < 16; ++c) {
            red[wv][c] = s[c];
            red[wv][16 + c] = ss[c];
        }
    }
    __syncthreads();
    if (t < 32) {
        float acc = 0.f;
#pragma unroll
        for (int w = 0; w < 16; ++w) acc += red[w][t];
        red[0][t] = acc;
    }
    __syncthreads();
    if (t < 16) {
        const float cnt = (float)(NB * NPTS * KNN);
        float mean = red[0][t] / cnt;
        float var = red[0][16 + t] / cnt - mean * mean;
        float sc = g[o0 + t] * (1.0f / sqrtf(var + EPSV));
        sctt[t] = sc;
        sctt[16 + t] = beta[o0 + t] - mean * sc;
    }
    __syncthreads();

    // ---- BN + lrelu, write val (and stage flat batches 0,1 for tp)
    unsigned vk[8];
#pragma unroll
    for (int c = 0; c < 16; ++c) {
        float sc = sctt[c], tt = sctt[16 + c];
        float e = (sc >= 0.f) ? mx[c] : mn[c];
        float z = sc * e + tt;
        z = z >= 0.f ? z : 0.2f * z;
        u16 hb = f16_bits(z);
        if (c & 1) vk[c >> 1] |= ((unsigned)hb << 16);
        else vk[c >> 1] = (unsigned)hb;
    }
    uint4 v0, v1;
    v0.x = vk[0]; v0.y = vk[1]; v0.z = vk[2]; v0.w = vk[3];
    v1.x = vk[4]; v1.y = vk[5]; v1.z = vk[6]; v1.w = vk[7];
    if (b < 2) {
        vls[b][n][0] = v0;
        vls[b][n][1] = v1;
    }
    long xbase = ((long)(b * NPTS + n)) * 8160 + offc + o0;
    *(uint4*)&xc[xbase] = v0;
    *(uint4*)&xc[xbase + 8] = v1;
    __syncthreads();

    // ---- tp = 0.5*(val[flat0]+val[flat1]) broadcast to all 4 batches
    uint4 a0 = vls[0][n][0], a1 = vls[0][n][1];
    uint4 b0 = vls[1][n][0], b1 = vls[1][n][1];
    unsigned pa[8] = {a0.x, a0.y, a0.z, a0.w, a1.x, a1.y, a1.z, a1.w};
    unsigned pb[8] = {b0.x, b0.y, b0.z, b0.w, b1.x, b1.y, b1.z, b1.w};
    unsigned tk[8];
#pragma unroll
    for (int c = 0; c < 16; ++c) {
        float va = (c & 1) ? f16_hi(pa[c >> 1]) : f16_lo(pa[c >> 1]);
        float vb = (c & 1) ? f16_hi(pb[c >> 1]) : f16_lo(pb[c >> 1]);
        u16 hb = f16_bits(0.5f * (va + vb));
        if (c & 1) tk[c >> 1] |= ((unsigned)hb << 16);
        else tk[c >> 1] = (unsigned)hb;
    }
    uint4 t0, t1;
    t0.x = tk[0]; t0.y = tk[1]; t0.z = tk[2]; t0.w = tk[3];
    t1.x = tk[4]; t1.y = tk[5]; t1.z = tk[6]; t1.w = tk[7];
    long tbase = ((long)(b * NPTS + n)) * 8160 + offc + Co + o0;
    *(uint4*)&xc[tbase] = t0;
    *(uint4*)&xc[tbase + 8] = t1;
}

// ---------------- final BN + lrelu -> fp32 out (sums 8 f16 y planes) --------
__global__ __launch_bounds__(256) void final_bn(const u16* __restrict__ y,
                                                const float* __restrict__ g4,
                                                const float* __restrict__ b4,
                                                float* __restrict__ out) {
    __shared__ float red[8];
    int o = blockIdx.x;
    int tid = threadIdx.x;
    int lane = tid & 63, w = tid >> 6;

    float v[4];
    float s = 0.f, ss = 0.f;
#pragma unroll
    for (int b = 0; b < 4; ++b) {
        float acc = 0.f;
#pragma unroll
        for (int sp = 0; sp < 8; ++sp)
            acc += f16_val(y[sp * 262144 + b * 65536 + o * 256 + tid]);
        v[b] = acc;
        s += acc;
        ss += acc * acc;
    }
#pragma unroll
    for (int off = 32; off; off >>= 1) {
        s += __shfl_xor(s, off);
        ss += __shfl_xor(ss, off);
    }
    if (lane == 0) { red[w] = s; red[4 + w] = ss; }
    __syncthreads();
    s = (red[0] + red[1]) + (red[2] + red[3]);
    ss = (red[4] + red[5]) + (red[6] + red[7]);
    float mean = s / 1024.f;
    float var = ss / 1024.f - mean * mean;
    float sc = g4[o] * (1.0f / sqrtf(var + EPSV));
    float tt = b4[o] - mean * sc;
#pragma unroll
    for (int b = 0; b < 4; ++b) {
        float z = sc * v[b] + tt;
        z = z >= 0.f ? z : 0.2f * z;
        out[(long)b * 65536 + o * 256 + tid] = z;
    }
}

// ---------------- launch ----------------
extern "C" void kernel_launch(void* const* d_in, const int* in_sizes, int n_in,
                              void* d_out, int out_size, void* d_ws, size_t ws_size,
                              hipStream_t stream) {
    const float* x = (const float*)d_in[0];
    const float* wl[4];
    const float* gl[4];
    const float* bl[4];
    for (int i = 0; i < 4; ++i) {
        wl[i] = (const float*)d_in[1 + 3 * i];
        gl[i] = (const float*)d_in[2 + 3 * i];
        bl[i] = (const float*)d_in[3 + 3 * i];
    }
    const float* w4 = (const float*)d_in[13];
    const float* g4 = (const float*)d_in[14];
    const float* b4 = (const float*)d_in[15];

    char* ws = (char*)d_ws;
    int* idxT = (int*)(ws + OFF_IDX);
    f16* xyz = (f16*)(ws + OFF_XYZ);
    u16* PQ = (u16*)(ws + OFF_PQ);
    f16* xc = (f16*)(ws + OFF_XC);
    u16* y = (u16*)(ws + OFF_Y);

    prep_knn<<<dim3(9472), dim3(256), 0, stream>>>(x, idxT, wl[0], wl[1], wl[2], wl[3], w4, ws);

    const int Kp[4] = {32, 96, 384, 1536};     // padded K (multiples of 32)
    const int Co[4] = {48, 192, 768, 3072};
    const int offc[4] = {0, 96, 480, 2016};
    const int inoff[4] = {0, 0, 96, 480};
    const int nsp[4] = {1, 3, 4, 3};
    const long aoff[4] = {OFF_A0, OFF_A1, OFF_A2, OFF_A3};

    for (int i = 0; i < 4; ++i) {
        int M = 2 * Co[i];
        int Mpad = (M + 127) & ~127;
        const f16* A = (const f16*)(ws + aoff[i]);

        const f16* Bp;
        int ldF;
        long bsF;
        if (i == 0) { Bp = xyz; ldF = 32; bsF = (long)NPTS * 32; }
        else { Bp = xc + inoff[i]; ldF = 8160; bsF = (long)NPTS * 8160; }

        long pstride = (long)NB * M * NPTS;   // one partial plane (elements)
        gemm_mfma<<<dim3(Mpad / 128, NPTS / 128, NB * nsp[i]), dim3(256), 0, stream>>>(
            A, Bp, PQ, M, Kp[i], Kp[i], ldF, bsF, (long)M * NPTS, nsp[i], pstride);

        gather16<<<dim3(Co[i] / 16), dim3(1024), 0, stream>>>(
            PQ, pstride, nsp[i], idxT, gl[i], bl[i], (u16*)xc, Co[i], offc[i]);
    }

    // final projection: split-K=8 into 8 private f16 y planes
    gemm_mfma<<<dim3(2, 2, NB * 8), dim3(256), 0, stream>>>(
        (const f16*)(ws + OFF_A4), xc, y, 256, 8160, 8160, 8160,
        (long)NPTS * 8160, (long)256 * NPTS, 8, (long)NB * 256 * NPTS);
    final_bn<<<dim3(256), dim3(256), 0, stream>>>(y, g4, b4, (float*)d_out);
}